// Round 5
// baseline (298.820 us; speedup 1.0000x reference)
//
#include <hip/hip_runtime.h>
#include <cstdint>
#include <cstddef>

#define BATCH 32
#define NCLS 81
#define NFG 80
#define NBOX 15130
#define NPAD 15360        // mask plane padded: 15×256×4, 16B-aligned uint4 rows
#define TOPK 200
#define NTASK (BATCH * NFG)
#define NEG_INF -1e30f
#define SORTCAP 1024      // max survivors per (image,class); measured mean ~434
#define SCORE_THR 0.05f
#define CRITERIA 0.45f

// ---------------------------------------------------------------- K1a: decode + softmax stats + logit threshold
// ROUND-2 LESSON: vals[81] must be DEAD after the sum loop (no later use) so
// it stays in registers; keeping it live spilled ~25 regs (990 us).
// ROUND-3 LESSON: no global atomics with few hot addresses (1900 us).
__global__ __launch_bounds__(256) void k1a_decode(
    const float* __restrict__ bboxes,   // [B,4,N]
    const float* __restrict__ scores,   // [B,C,N]
    const float* __restrict__ dboxes,   // [N,4]
    float4* __restrict__ ltrb,          // [B*N]
    float2* __restrict__ stats,         // [B*N] (max, denom)
    float* __restrict__ thr)            // [B*N] logit threshold
{
    int g = blockIdx.x * blockDim.x + threadIdx.x;
    if (g >= BATCH * NBOX) return;
    int b = g / NBOX;
    int n = g - b * NBOX;

    const float* bb = bboxes + (size_t)b * 4 * NBOX + n;
    float bx = bb[0];
    float by = bb[NBOX];
    float bw = bb[2 * (size_t)NBOX];
    float bh = bb[3 * (size_t)NBOX];
    float4 d = reinterpret_cast<const float4*>(dboxes)[n];  // cx, cy, w, h
    float xx = __fadd_rn(__fmul_rn(__fmul_rn(0.1f, bx), d.z), d.x);
    float yy = __fadd_rn(__fmul_rn(__fmul_rn(0.1f, by), d.w), d.y);
    float wx = __fmul_rn(expf(__fmul_rn(0.2f, bw)), d.z);
    float wy = __fmul_rn(expf(__fmul_rn(0.2f, bh)), d.w);
    float4 o;
    o.x = __fsub_rn(xx, __fmul_rn(0.5f, wx));
    o.y = __fsub_rn(yy, __fmul_rn(0.5f, wy));
    o.z = __fadd_rn(xx, __fmul_rn(0.5f, wx));
    o.w = __fadd_rn(yy, __fmul_rn(0.5f, wy));
    ltrb[g] = o;

    const float* sc = scores + (size_t)b * NCLS * NBOX + n;
    float vals[NCLS];
#pragma unroll
    for (int c = 0; c < NCLS; ++c) vals[c] = sc[(size_t)c * NBOX];
    float m = vals[0];
#pragma unroll
    for (int c = 1; c < NCLS; ++c) m = fmaxf(m, vals[c]);
    float s = 0.0f;
#pragma unroll
    for (int c = 0; c < NCLS; ++c) s = __fadd_rn(s, expf(__fsub_rn(vals[c], m)));
    stats[g] = make_float2(m, s);
    // p > 0.05  =>  v > m + log(0.05*s); margin 1e-3 >> logf error; mask is a
    // SUPERSET — k2 re-tests survivors with the exact reference expression.
    thr[g] = __fsub_rn(__fadd_rn(m, logf(__fmul_rn(0.05f, s))), 1e-3f);
}

// ---------------------------------------------------------------- K1b: build per-box class-survival bitmask
// One thread per box; 80 independent re-reads of the (L3-hot) score column,
// bits accumulate in 3 registers (nothing held live -> no spill).
__global__ __launch_bounds__(256) void k1b_mask(
    const float* __restrict__ scores,   // [B,C,N]
    const float* __restrict__ thr,      // [B*N]
    unsigned* __restrict__ maskw)       // [3][B][NPAD]
{
    const int blk = blockIdx.x;         // b*60 + chunk
    const int b = blk / 60;
    const int chunk = blk - b * 60;
    const int n = chunk * 256 + threadIdx.x;
    if (n >= NBOX) return;

    const float tv = thr[b * NBOX + n];
    const float* sc = scores + (size_t)b * NCLS * NBOX + n;
    unsigned w0 = 0, w1 = 0, w2 = 0;
#pragma unroll
    for (int c = 1; c < 32; ++c)
        if (sc[(size_t)c * NBOX] > tv) w0 |= 1u << c;
#pragma unroll
    for (int c = 32; c < 64; ++c)
        if (sc[(size_t)c * NBOX] > tv) w1 |= 1u << (c - 32);
#pragma unroll
    for (int c = 64; c < NCLS; ++c)
        if (sc[(size_t)c * NBOX] > tv) w2 |= 1u << (c - 64);

    const size_t base = (size_t)b * NPAD + n;
    maskw[base] = w0;
    maskw[(size_t)BATCH * NPAD + base] = w1;
    maskw[2 * (size_t)BATCH * NPAD + base] = w2;
}

// ---------------------------------------------------------------- K2: per-(image,class) mask-scan + sort + NMS
__global__ __launch_bounds__(256) void k2_nms(
    const unsigned* __restrict__ maskw,     // [3][B][NPAD]
    const float* __restrict__ scores,       // [B,C,N] (survivors only)
    const float2* __restrict__ stats,       // [B*N]
    const float4* __restrict__ ltrb,        // [B*N]
    float* __restrict__ cls_scores,         // [NTASK*200]
    int* __restrict__ cls_idx)              // [NTASK*200] global ltrb index
{
    const int t = blockIdx.x;       // task = b*80 + (c-1)
    const int b = t / NFG;
    const int c = t - b * NFG + 1;  // class 1..80
    const int tid = threadIdx.x;

    // cand is dead after Phase C; mrow aliases it (saves 6.4 KB LDS)
    __shared__ unsigned long long cand[SORTCAP];            // 8 KB
    unsigned long long (*mrow)[4] = (unsigned long long(*)[4])cand;  // [200][4] = 6.4 KB
    __shared__ int cnt;
    __shared__ float4 sbox[TOPK];
    __shared__ float sarea[TOPK];
    __shared__ float sscore[TOPK];
    __shared__ int sidx[TOPK];
    __shared__ unsigned long long keepw[4];

    if (tid == 0) cnt = 0;
    __syncthreads();

    // Phase A: uint4 scan of the class's mask-plane row (L2/L3-resident).
    // Survivors (~3%) load score+stats and run the exact reference test.
    const uint4* mrow4 = (const uint4*)(maskw + (size_t)(c >> 5) * BATCH * NPAD + (size_t)b * NPAD);
    const float* srow = scores + ((size_t)b * NCLS + c) * NBOX;
    const float2* st = stats + (size_t)b * NBOX;
    const unsigned bit = 1u << (c & 31);

#define TRY_EMIT(WORD, NN)                                                        \
    if (((WORD) & bit) && (NN) < NBOX) {                                          \
        float v = srow[(NN)];                                                     \
        float2 md = st[(NN)];                                                     \
        float p = __fdiv_rn(expf(__fsub_rn(v, md.x)), md.y);                      \
        if (p > SCORE_THR) {                                                      \
            int pos = atomicAdd(&cnt, 1);                                         \
            if (pos < SORTCAP)                                                    \
                cand[pos] = ((unsigned long long)__float_as_uint(p) << 32) |      \
                            (unsigned long long)(0xFFFFFFFFu - (unsigned)(NN));   \
        }                                                                         \
    }

#pragma unroll 5
    for (int it = 0; it < 15; ++it) {       // NPAD/4/256 = 15 exactly
        int i = it * 256 + tid;             // uint4 index
        uint4 mw = mrow4[i];
        int n0 = i * 4;
        if ((mw.x | mw.y | mw.z | mw.w) & bit) {
            TRY_EMIT(mw.x, n0)
            TRY_EMIT(mw.y, n0 + 1)
            TRY_EMIT(mw.z, n0 + 2)
            TRY_EMIT(mw.w, n0 + 3)
        }
    }
#undef TRY_EMIT
    __syncthreads();

    const int cl = min(cnt, SORTCAP);
    unsigned sz = 2;
    while (sz < (unsigned)cl) sz <<= 1;

    for (unsigned i = (unsigned)cl + tid; i < sz; i += 256) cand[i] = 0ULL;
    __syncthreads();

    // Phase B: bitonic sort descending (score desc, idx asc) — keys unique => deterministic
    for (unsigned k = 2; k <= sz; k <<= 1) {
        for (unsigned j = k >> 1; j > 0; j >>= 1) {
            for (unsigned i = tid; i < sz; i += 256) {
                unsigned ixj = i ^ j;
                if (ixj > i) {
                    unsigned long long a = cand[i], bb2 = cand[ixj];
                    bool desc = ((i & k) == 0);
                    if (desc ? (a < bb2) : (a > bb2)) { cand[i] = bb2; cand[ixj] = a; }
                }
            }
            __syncthreads();
        }
    }

    const int mk = min(cl, TOPK);

    // Phase C: gather boxes for top-mk (cand dead after this)
    if (tid < mk) {
        unsigned long long key = cand[tid];
        unsigned n = 0xFFFFFFFFu - (unsigned)(key & 0xFFFFFFFFull);
        float4 bx = ltrb[(size_t)b * NBOX + n];
        sbox[tid] = bx;
        sarea[tid] = __fmul_rn(__fsub_rn(bx.z, bx.x), __fsub_rn(bx.w, bx.y));
        sscore[tid] = __uint_as_float((unsigned)(key >> 32));
        sidx[tid] = b * NBOX + (int)n;
    }
    __syncthreads();

    // Phase D: suppression bitmask rows (IoU replicates reference's unclamped deltas)
    if (tid < mk) {
        float4 bi = sbox[tid];
        float ai = sarea[tid];
#pragma unroll
        for (int q = 0; q < 4; ++q) {
            unsigned long long w = 0ULL;
            int j0 = q * 64;
            int j1 = min(mk, j0 + 64);
            for (int j2 = max(tid + 1, j0); j2 < j1; ++j2) {
                float4 bj = sbox[j2];
                float ltx = fmaxf(bi.x, bj.x), lty = fmaxf(bi.y, bj.y);
                float rbx = fminf(bi.z, bj.z), rby = fminf(bi.w, bj.w);
                float dx = __fsub_rn(rbx, ltx), dy = __fsub_rn(rby, lty);
                float inter = __fmul_rn(dx, dy);
                float uni = __fsub_rn(__fadd_rn(ai, sarea[j2]), inter);
                float iou = __fdiv_rn(inter, uni);
                if (iou >= CRITERIA) w |= 1ULL << (j2 - j0);
            }
            mrow[tid][q] = w;
        }
    }
    __syncthreads();

    // Phase E: greedy sequential pass (thread 0, LDS prefetch one row ahead)
    if (tid == 0) {
        auto maskBits = [](int r) -> unsigned long long {
            if (r <= 0) return 0ULL;
            if (r >= 64) return ~0ULL;
            return (1ULL << r) - 1ULL;
        };
        unsigned long long kw0 = maskBits(mk);
        unsigned long long kw1 = maskBits(mk - 64);
        unsigned long long kw2 = maskBits(mk - 128);
        unsigned long long kw3 = maskBits(mk - 192);
        unsigned long long r0 = 0, r1 = 0, r2 = 0, r3 = 0;
        if (mk > 0) { r0 = mrow[0][0]; r1 = mrow[0][1]; r2 = mrow[0][2]; r3 = mrow[0][3]; }
#define GREEDY_WORD(KW, BASE)                                                     \
        for (int bit2 = 0; bit2 < 64; ++bit2) {                                   \
            int i = (BASE) + bit2;                                                \
            if (i >= mk) break;                                                   \
            int ip = (i + 1 < mk) ? (i + 1) : i;                                  \
            unsigned long long n0 = mrow[ip][0], n1 = mrow[ip][1],                \
                               n2 = mrow[ip][2], n3 = mrow[ip][3];                \
            if ((KW >> bit2) & 1ULL) {                                            \
                kw0 &= ~r0; kw1 &= ~r1; kw2 &= ~r2; kw3 &= ~r3;                   \
            }                                                                     \
            r0 = n0; r1 = n1; r2 = n2; r3 = n3;                                   \
        }
        GREEDY_WORD(kw0, 0)
        GREEDY_WORD(kw1, 64)
        GREEDY_WORD(kw2, 128)
        GREEDY_WORD(kw3, 192)
#undef GREEDY_WORD
        keepw[0] = kw0; keepw[1] = kw1; keepw[2] = kw2; keepw[3] = kw3;
    }
    __syncthreads();

    // Phase F: write per-class results
    if (tid < TOPK) {
        float s = NEG_INF;
        if (tid < mk && ((keepw[tid >> 6] >> (tid & 63)) & 1ULL)) s = sscore[tid];
        cls_scores[(size_t)t * TOPK + tid] = s;
        if (tid < mk) cls_idx[(size_t)t * TOPK + tid] = sidx[tid];
    }
}

// ---------------------------------------------------------------- K3: per-image global top-200
__device__ __forceinline__ int blockReduceSum(int x, int* red, int tid) {
    __syncthreads();
    red[tid] = x;
    __syncthreads();
    for (int off = 128; off > 0; off >>= 1) {
        if (tid < off) red[tid] += red[tid + off];
        __syncthreads();
    }
    return red[0];
}

__global__ __launch_bounds__(256) void k3_topk(
    const float* __restrict__ cls_scores,   // [B*80*200]
    const int* __restrict__ cls_idx,        // [B*80*200]
    const float4* __restrict__ ltrb,        // [B*N]
    float* __restrict__ out)
{
    const int b = blockIdx.x;
    const int tid = threadIdx.x;
    const int NFLAT = NFG * TOPK;           // 16000
    const int PER = 63;

    __shared__ unsigned long long sel[512];
    __shared__ int scnt;
    __shared__ int red[256];

    const float* S = cls_scores + (size_t)b * NFLAT;
    float v[PER];
#pragma unroll
    for (int i = 0; i < PER; ++i) {
        int j = i * 256 + tid;
        v[i] = (j < NFLAT) ? S[j] : NEG_INF;
    }

    int lc = 0;
#pragma unroll
    for (int i = 0; i < PER; ++i) lc += (v[i] > -1e29f) ? 1 : 0;
    int validCount = blockReduceSum(lc, red, tid);

    unsigned thrBits = 0;
    if (validCount > TOPK) {
        unsigned lo = 0, hi = 0x7F800000u;
        while (lo < hi) {
            unsigned mid = (lo + hi) >> 1;
            float mf = __uint_as_float(mid);
            int c2 = 0;
#pragma unroll
            for (int i = 0; i < PER; ++i) c2 += (v[i] > mf) ? 1 : 0;
            int tot = blockReduceSum(c2, red, tid);
            if (tot < TOPK) hi = mid; else lo = mid + 1;
        }
        thrBits = lo;
    }

    __syncthreads();
    if (tid == 0) scnt = 0;
    for (int i = tid; i < 512; i += 256) sel[i] = 0ULL;
    __syncthreads();

    const bool useGE = (validCount > TOPK);
    const float thrF = __uint_as_float(thrBits);
#pragma unroll
    for (int i = 0; i < PER; ++i) {
        int j = i * 256 + tid;
        bool take = useGE ? (v[i] >= thrF) : (v[i] > -1e29f);
        if (j < NFLAT && take) {
            int pos = atomicAdd(&scnt, 1);
            if (pos < 512) {
                sel[pos] = ((unsigned long long)__float_as_uint(v[i]) << 32) |
                           (unsigned long long)(0xFFFFFFFFu - (unsigned)j);
            }
        }
    }
    __syncthreads();
    int total = min(min(scnt, 512), TOPK);

    for (unsigned k = 2; k <= 512; k <<= 1) {
        for (unsigned j = k >> 1; j > 0; j >>= 1) {
            for (unsigned i = tid; i < 512; i += 256) {
                unsigned ixj = i ^ j;
                if (ixj > i) {
                    unsigned long long a = sel[i], bb2 = sel[ixj];
                    bool desc = ((i & k) == 0);
                    if (desc ? (a < bb2) : (a > bb2)) { sel[i] = bb2; sel[ixj] = a; }
                }
            }
            __syncthreads();
        }
    }

    if (tid < TOPK) {
        size_t ob = (size_t)b * TOPK + tid;
        float4 bx = make_float4(0.f, 0.f, 0.f, 0.f);
        float lab = 0.f, sc2 = 0.f;
        if (tid < total) {
            unsigned long long key = sel[tid];
            unsigned j = 0xFFFFFFFFu - (unsigned)(key & 0xFFFFFFFFull);
            sc2 = __uint_as_float((unsigned)(key >> 32));
            unsigned cls = j / TOPK;
            int gi = cls_idx[(size_t)b * NFLAT + j];
            bx = ltrb[gi];
            lab = (float)(cls + 1);
        }
        reinterpret_cast<float4*>(out)[ob] = bx;
        out[(size_t)BATCH * TOPK * 4 + ob] = lab;
        out[(size_t)BATCH * TOPK * 4 + (size_t)BATCH * TOPK + ob] = sc2;
    }
}

// ---------------------------------------------------------------- launch
extern "C" void kernel_launch(void* const* d_in, const int* in_sizes, int n_in,
                              void* d_out, int out_size, void* d_ws, size_t ws_size,
                              hipStream_t stream) {
    (void)in_sizes; (void)n_in; (void)out_size; (void)ws_size;
    const float* bboxes = (const float*)d_in[0];   // [32,4,15130]
    const float* scores = (const float*)d_in[1];   // [32,81,15130]
    const float* dboxes = (const float*)d_in[2];   // [1,15130,4]
    float* out = (float*)d_out;

    char* ws = (char*)d_ws;
    size_t off = 0;
    float4* ltrb = (float4*)(ws + off);      off += (size_t)BATCH * NBOX * 16;      //  7,746,560
    float2* stats = (float2*)(ws + off);     off += (size_t)BATCH * NBOX * 8;       //  3,873,280
    float*  thr   = (float*)(ws + off);      off += (size_t)BATCH * NBOX * 4;       //  1,936,640
    unsigned* maskw = (unsigned*)(ws + off); off += 3ull * BATCH * NPAD * 4;        //  5,898,240
    float* cls_scores = (float*)(ws + off);  off += (size_t)NTASK * TOPK * 4;       //  2,048,000
    int*   cls_idx    = (int*)(ws + off);    off += (size_t)NTASK * TOPK * 4;       //  2,048,000

    int g1 = (BATCH * NBOX + 255) / 256;
    k1a_decode<<<g1, 256, 0, stream>>>(bboxes, scores, dboxes, ltrb, stats, thr);
    k1b_mask<<<BATCH * 60, 256, 0, stream>>>(scores, thr, maskw);
    k2_nms<<<NTASK, 256, 0, stream>>>(maskw, scores, stats, ltrb, cls_scores, cls_idx);
    k3_topk<<<BATCH, 256, 0, stream>>>(cls_scores, cls_idx, ltrb, out);
}

// Round 6
// 269.107 us; speedup vs baseline: 1.1104x; 1.1104x over previous
//
#include <hip/hip_runtime.h>
#include <cstdint>
#include <cstddef>

#define BATCH 32
#define NCLS 81
#define NFG 80
#define NBOX 15130
#define NPAD 15360        // padded per-image stride for thr/stats (float2/float4 alignment)
#define NF2 (NBOX / 2)    // 7565 float2 elements per score row
#define TOPK 200
#define NTASK (BATCH * NFG)
#define NEG_INF -1e30f
#define SORTCAP 1024      // max survivors per (image,class); measured mean ~434, max < 768
#define SCORE_THR 0.05f
#define CRITERIA 0.45f

// ---------------------------------------------------------------- K1a: decode + softmax stats + logit threshold
// ROUND-2 LESSON: vals[81] must be DEAD after the sum loop (no later use) so
// it stays in registers; keeping it live spilled ~25 regs (990 us).
// ROUND-3 LESSON: no global atomics with few hot addresses (1900 us).
__global__ __launch_bounds__(256) void k1a_decode(
    const float* __restrict__ bboxes,   // [B,4,N]
    const float* __restrict__ scores,   // [B,C,N]
    const float* __restrict__ dboxes,   // [N,4]
    float4* __restrict__ ltrb,          // [B*N]
    float2* __restrict__ stats,         // [B][NPAD] (max, denom)
    float* __restrict__ thr)            // [B][NPAD] logit threshold
{
    int g = blockIdx.x * blockDim.x + threadIdx.x;
    if (g >= BATCH * NBOX) return;
    int b = g / NBOX;
    int n = g - b * NBOX;

    const float* bb = bboxes + (size_t)b * 4 * NBOX + n;
    float bx = bb[0];
    float by = bb[NBOX];
    float bw = bb[2 * (size_t)NBOX];
    float bh = bb[3 * (size_t)NBOX];
    float4 d = reinterpret_cast<const float4*>(dboxes)[n];  // cx, cy, w, h
    float xx = __fadd_rn(__fmul_rn(__fmul_rn(0.1f, bx), d.z), d.x);
    float yy = __fadd_rn(__fmul_rn(__fmul_rn(0.1f, by), d.w), d.y);
    float wx = __fmul_rn(expf(__fmul_rn(0.2f, bw)), d.z);
    float wy = __fmul_rn(expf(__fmul_rn(0.2f, bh)), d.w);
    float4 o;
    o.x = __fsub_rn(xx, __fmul_rn(0.5f, wx));
    o.y = __fsub_rn(yy, __fmul_rn(0.5f, wy));
    o.z = __fadd_rn(xx, __fmul_rn(0.5f, wx));
    o.w = __fadd_rn(yy, __fmul_rn(0.5f, wy));
    ltrb[g] = o;

    const float* sc = scores + (size_t)b * NCLS * NBOX + n;
    float vals[NCLS];
#pragma unroll
    for (int c = 0; c < NCLS; ++c) vals[c] = sc[(size_t)c * NBOX];
    float m = vals[0];
#pragma unroll
    for (int c = 1; c < NCLS; ++c) m = fmaxf(m, vals[c]);
    float s = 0.0f;
#pragma unroll
    for (int c = 0; c < NCLS; ++c) s = __fadd_rn(s, expf(__fsub_rn(vals[c], m)));
    stats[(size_t)b * NPAD + n] = make_float2(m, s);
    // p > 0.05  =>  v > m + log(0.05*s); margin 1e-3 >> logf error; survivors
    // are re-tested in k2 with the exact reference expression.
    thr[(size_t)b * NPAD + n] = __fsub_rn(__fadd_rn(m, logf(__fmul_rn(0.05f, s))), 1e-3f);
}

// ---------------------------------------------------------------- K2: per-(image,class) MLP-scan + sort + NMS
// ROUND-4/5 LESSON: the scan must have explicit memory-level parallelism.
// Scalar (or conditional scattered) loads leave ~2 loads in flight per
// thread -> latency-bound at ~600 GB/s. Batch 12 independent float2 loads
// (v + thr) into registers BEFORE any test. Survivor-only data (stats) is
// L2-resident (3.9 MB).
__global__ __launch_bounds__(256) void k2_nms(
    const float* __restrict__ scores,       // [B,C,N]
    const float* __restrict__ thr,          // [B][NPAD]
    const float2* __restrict__ stats,       // [B][NPAD]
    const float4* __restrict__ ltrb,        // [B*N]
    float* __restrict__ cls_scores,         // [NTASK*200]
    int* __restrict__ cls_idx)              // [NTASK*200] global ltrb index
{
    const int t = blockIdx.x;       // task = b*80 + (c-1)
    const int b = t / NFG;
    const int c = t - b * NFG + 1;  // class 1..80
    const int tid = threadIdx.x;

    // cand is dead after Phase C; mrow aliases it (saves 6.4 KB LDS)
    __shared__ unsigned long long cand[SORTCAP];                     // 8 KB
    unsigned long long (*mrow)[4] = (unsigned long long(*)[4])cand;  // [200][4]
    __shared__ int cnt;
    __shared__ float4 sbox[TOPK];
    __shared__ float sarea[TOPK];
    __shared__ float sscore[TOPK];
    __shared__ int sidx[TOPK];
    __shared__ unsigned long long keepw[4];

    if (tid == 0) cnt = 0;
    __syncthreads();

    // Phase A: batched float2 scan. Row base (b*81+c)*15130 is 8B-aligned
    // (NBOX even) -> float2 loads legal. thr/stats use NPAD stride (aligned).
    const float2* srow2 = (const float2*)(scores + ((size_t)b * NCLS + c) * NBOX);
    const float2* trow2 = (const float2*)(thr + (size_t)b * NPAD);
    const float2* st = stats + (size_t)b * NPAD;

    auto emit = [&](int n, float v) {
        float2 md = st[n];
        // exact test — identical expression to the validated round-1 kernel
        float p = __fdiv_rn(expf(__fsub_rn(v, md.x)), md.y);
        if (p > SCORE_THR) {
            int pos = atomicAdd(&cnt, 1);
            if (pos < SORTCAP)
                cand[pos] = ((unsigned long long)__float_as_uint(p) << 32) |
                            (unsigned long long)(0xFFFFFFFFu - (unsigned)n);
        }
    };

    for (int bb = 0; bb < 5; ++bb) {        // 5 batches x 6 x 256 = 7680 >= NF2
        const int i0 = bb * 1536 + tid;
        float2 v[6], w[6];
#pragma unroll
        for (int u = 0; u < 6; ++u) {
            int i = i0 + u * 256;
            if (i < NF2) { v[u] = srow2[i]; w[u] = trow2[i]; }
            else { v[u] = make_float2(0.f, 0.f); w[u] = make_float2(1e30f, 1e30f); }
        }
#pragma unroll
        for (int u = 0; u < 6; ++u) {
            int i = i0 + u * 256;
            if (v[u].x > w[u].x) emit(2 * i, v[u].x);
            if (v[u].y > w[u].y) emit(2 * i + 1, v[u].y);
        }
    }
    __syncthreads();

    const int cl = min(cnt, SORTCAP);
    unsigned sz = 2;
    while (sz < (unsigned)cl) sz <<= 1;

    for (unsigned i = (unsigned)cl + tid; i < sz; i += 256) cand[i] = 0ULL;
    __syncthreads();

    // Phase B: bitonic sort descending (score desc, idx asc) — keys unique => deterministic
    for (unsigned k = 2; k <= sz; k <<= 1) {
        for (unsigned j = k >> 1; j > 0; j >>= 1) {
            for (unsigned i = tid; i < sz; i += 256) {
                unsigned ixj = i ^ j;
                if (ixj > i) {
                    unsigned long long a = cand[i], bb2 = cand[ixj];
                    bool desc = ((i & k) == 0);
                    if (desc ? (a < bb2) : (a > bb2)) { cand[i] = bb2; cand[ixj] = a; }
                }
            }
            __syncthreads();
        }
    }

    const int mk = min(cl, TOPK);

    // Phase C: gather boxes for top-mk (cand dead after this)
    if (tid < mk) {
        unsigned long long key = cand[tid];
        unsigned n = 0xFFFFFFFFu - (unsigned)(key & 0xFFFFFFFFull);
        float4 bx = ltrb[(size_t)b * NBOX + n];
        sbox[tid] = bx;
        sarea[tid] = __fmul_rn(__fsub_rn(bx.z, bx.x), __fsub_rn(bx.w, bx.y));
        sscore[tid] = __uint_as_float((unsigned)(key >> 32));
        sidx[tid] = b * NBOX + (int)n;
    }
    __syncthreads();

    // Phase D: suppression bitmask rows (IoU replicates reference's unclamped deltas)
    if (tid < mk) {
        float4 bi = sbox[tid];
        float ai = sarea[tid];
#pragma unroll
        for (int q = 0; q < 4; ++q) {
            unsigned long long w = 0ULL;
            int j0 = q * 64;
            int j1 = min(mk, j0 + 64);
            for (int j2 = max(tid + 1, j0); j2 < j1; ++j2) {
                float4 bj = sbox[j2];
                float ltx = fmaxf(bi.x, bj.x), lty = fmaxf(bi.y, bj.y);
                float rbx = fminf(bi.z, bj.z), rby = fminf(bi.w, bj.w);
                float dx = __fsub_rn(rbx, ltx), dy = __fsub_rn(rby, lty);
                float inter = __fmul_rn(dx, dy);
                float uni = __fsub_rn(__fadd_rn(ai, sarea[j2]), inter);
                float iou = __fdiv_rn(inter, uni);
                if (iou >= CRITERIA) w |= 1ULL << (j2 - j0);
            }
            mrow[tid][q] = w;
        }
    }
    __syncthreads();

    // Phase E: greedy sequential pass (thread 0, LDS prefetch one row ahead)
    if (tid == 0) {
        auto maskBits = [](int r) -> unsigned long long {
            if (r <= 0) return 0ULL;
            if (r >= 64) return ~0ULL;
            return (1ULL << r) - 1ULL;
        };
        unsigned long long kw0 = maskBits(mk);
        unsigned long long kw1 = maskBits(mk - 64);
        unsigned long long kw2 = maskBits(mk - 128);
        unsigned long long kw3 = maskBits(mk - 192);
        unsigned long long r0 = 0, r1 = 0, r2 = 0, r3 = 0;
        if (mk > 0) { r0 = mrow[0][0]; r1 = mrow[0][1]; r2 = mrow[0][2]; r3 = mrow[0][3]; }
#define GREEDY_WORD(KW, BASE)                                                     \
        for (int bit2 = 0; bit2 < 64; ++bit2) {                                   \
            int i = (BASE) + bit2;                                                \
            if (i >= mk) break;                                                   \
            int ip = (i + 1 < mk) ? (i + 1) : i;                                  \
            unsigned long long n0 = mrow[ip][0], n1 = mrow[ip][1],                \
                               n2 = mrow[ip][2], n3 = mrow[ip][3];                \
            if ((KW >> bit2) & 1ULL) {                                            \
                kw0 &= ~r0; kw1 &= ~r1; kw2 &= ~r2; kw3 &= ~r3;                   \
            }                                                                     \
            r0 = n0; r1 = n1; r2 = n2; r3 = n3;                                   \
        }
        GREEDY_WORD(kw0, 0)
        GREEDY_WORD(kw1, 64)
        GREEDY_WORD(kw2, 128)
        GREEDY_WORD(kw3, 192)
#undef GREEDY_WORD
        keepw[0] = kw0; keepw[1] = kw1; keepw[2] = kw2; keepw[3] = kw3;
    }
    __syncthreads();

    // Phase F: write per-class results
    if (tid < TOPK) {
        float s = NEG_INF;
        if (tid < mk && ((keepw[tid >> 6] >> (tid & 63)) & 1ULL)) s = sscore[tid];
        cls_scores[(size_t)t * TOPK + tid] = s;
        if (tid < mk) cls_idx[(size_t)t * TOPK + tid] = sidx[tid];
    }
}

// ---------------------------------------------------------------- K3: per-image global top-200
__device__ __forceinline__ int blockReduceSum(int x, int* red, int tid) {
    __syncthreads();
    red[tid] = x;
    __syncthreads();
    for (int off = 128; off > 0; off >>= 1) {
        if (tid < off) red[tid] += red[tid + off];
        __syncthreads();
    }
    return red[0];
}

__global__ __launch_bounds__(256) void k3_topk(
    const float* __restrict__ cls_scores,   // [B*80*200]
    const int* __restrict__ cls_idx,        // [B*80*200]
    const float4* __restrict__ ltrb,        // [B*N]
    float* __restrict__ out)
{
    const int b = blockIdx.x;
    const int tid = threadIdx.x;
    const int NFLAT = NFG * TOPK;           // 16000
    const int PER = 63;

    __shared__ unsigned long long sel[512];
    __shared__ int scnt;
    __shared__ int red[256];

    const float* S = cls_scores + (size_t)b * NFLAT;
    float v[PER];
#pragma unroll
    for (int i = 0; i < PER; ++i) {
        int j = i * 256 + tid;
        v[i] = (j < NFLAT) ? S[j] : NEG_INF;
    }

    int lc = 0;
#pragma unroll
    for (int i = 0; i < PER; ++i) lc += (v[i] > -1e29f) ? 1 : 0;
    int validCount = blockReduceSum(lc, red, tid);

    unsigned thrBits = 0;
    if (validCount > TOPK) {
        unsigned lo = 0, hi = 0x7F800000u;
        while (lo < hi) {
            unsigned mid = (lo + hi) >> 1;
            float mf = __uint_as_float(mid);
            int c2 = 0;
#pragma unroll
            for (int i = 0; i < PER; ++i) c2 += (v[i] > mf) ? 1 : 0;
            int tot = blockReduceSum(c2, red, tid);
            if (tot < TOPK) hi = mid; else lo = mid + 1;
        }
        thrBits = lo;
    }

    __syncthreads();
    if (tid == 0) scnt = 0;
    for (int i = tid; i < 512; i += 256) sel[i] = 0ULL;
    __syncthreads();

    const bool useGE = (validCount > TOPK);
    const float thrF = __uint_as_float(thrBits);
#pragma unroll
    for (int i = 0; i < PER; ++i) {
        int j = i * 256 + tid;
        bool take = useGE ? (v[i] >= thrF) : (v[i] > -1e29f);
        if (j < NFLAT && take) {
            int pos = atomicAdd(&scnt, 1);
            if (pos < 512) {
                sel[pos] = ((unsigned long long)__float_as_uint(v[i]) << 32) |
                           (unsigned long long)(0xFFFFFFFFu - (unsigned)j);
            }
        }
    }
    __syncthreads();
    int total = min(min(scnt, 512), TOPK);

    for (unsigned k = 2; k <= 512; k <<= 1) {
        for (unsigned j = k >> 1; j > 0; j >>= 1) {
            for (unsigned i = tid; i < 512; i += 256) {
                unsigned ixj = i ^ j;
                if (ixj > i) {
                    unsigned long long a = sel[i], bb2 = sel[ixj];
                    bool desc = ((i & k) == 0);
                    if (desc ? (a < bb2) : (a > bb2)) { sel[i] = bb2; sel[ixj] = a; }
                }
            }
            __syncthreads();
        }
    }

    if (tid < TOPK) {
        size_t ob = (size_t)b * TOPK + tid;
        float4 bx = make_float4(0.f, 0.f, 0.f, 0.f);
        float lab = 0.f, sc2 = 0.f;
        if (tid < total) {
            unsigned long long key = sel[tid];
            unsigned j = 0xFFFFFFFFu - (unsigned)(key & 0xFFFFFFFFull);
            sc2 = __uint_as_float((unsigned)(key >> 32));
            unsigned cls = j / TOPK;
            int gi = cls_idx[(size_t)b * NFLAT + j];
            bx = ltrb[gi];
            lab = (float)(cls + 1);
        }
        reinterpret_cast<float4*>(out)[ob] = bx;
        out[(size_t)BATCH * TOPK * 4 + ob] = lab;
        out[(size_t)BATCH * TOPK * 4 + (size_t)BATCH * TOPK + ob] = sc2;
    }
}

// ---------------------------------------------------------------- launch
extern "C" void kernel_launch(void* const* d_in, const int* in_sizes, int n_in,
                              void* d_out, int out_size, void* d_ws, size_t ws_size,
                              hipStream_t stream) {
    (void)in_sizes; (void)n_in; (void)out_size; (void)ws_size;
    const float* bboxes = (const float*)d_in[0];   // [32,4,15130]
    const float* scores = (const float*)d_in[1];   // [32,81,15130]
    const float* dboxes = (const float*)d_in[2];   // [1,15130,4]
    float* out = (float*)d_out;

    char* ws = (char*)d_ws;
    size_t off = 0;
    float4* ltrb = (float4*)(ws + off);      off += (size_t)BATCH * NBOX * 16;    //  7,746,560
    float2* stats = (float2*)(ws + off);     off += (size_t)BATCH * NPAD * 8;     //  3,932,160
    float*  thr   = (float*)(ws + off);      off += (size_t)BATCH * NPAD * 4;     //  1,966,080
    float* cls_scores = (float*)(ws + off);  off += (size_t)NTASK * TOPK * 4;     //  2,048,000
    int*   cls_idx    = (int*)(ws + off);    off += (size_t)NTASK * TOPK * 4;     //  2,048,000

    int g1 = (BATCH * NBOX + 255) / 256;
    k1a_decode<<<g1, 256, 0, stream>>>(bboxes, scores, dboxes, ltrb, stats, thr);
    k2_nms<<<NTASK, 256, 0, stream>>>(scores, thr, stats, ltrb, cls_scores, cls_idx);
    k3_topk<<<BATCH, 256, 0, stream>>>(cls_scores, cls_idx, ltrb, out);
}

// Round 7
// 258.181 us; speedup vs baseline: 1.1574x; 1.0423x over previous
//
#include <hip/hip_runtime.h>
#include <cstdint>
#include <cstddef>

#define BATCH 32
#define NCLS 81
#define NFG 80
#define NBOX 15130
#define NCHUNK 60         // ceil(15130/256)
#define TOPK 200
#define NTASK (BATCH * NFG)
#define NEG_INF -1e30f
#define GCAP 1024         // per-task candidate capacity (measured mean ~434)
#define SORTCAP 1024
#define LCAP 4864         // 256 boxes * max 19 classes/box (hard bound: sum p = 1)
#define SCORE_THR 0.05f
#define CRITERIA 0.45f

// ---------------------------------------------------------------- K1: decode + softmax + compacted candidate emission
// ROUND-2 LESSON: vals[81] must be DEAD after the sum loop; the phase-3
// re-read goes through an asm-laundered pointer so the compiler cannot CSE
// it back to vals[] and extend liveness (spill -> 990 us).
// ROUND-3 LESSON: no per-element global atomics on few hot addresses
// (1900 us). Emission batches ONE global atomicAdd per (block,class).
// ROUND-4/5/6 LESSON: per-(b,c) blocks must not re-stream 60 KB each from
// the L2-miss path (~115 us floor); k2 now reads ~3.5 KB compacted lists.
__global__ __launch_bounds__(256) void k1_fused(
    const float* __restrict__ bboxes,   // [B,4,N]
    const float* __restrict__ scores,   // [B,C,N]
    const float* __restrict__ dboxes,   // [N,4]
    float4* __restrict__ ltrb,          // [B*N]
    unsigned long long* __restrict__ gcand,  // [NTASK*GCAP]
    int* __restrict__ gcnt)             // [NTASK] (zeroed before launch)
{
    const int blk = blockIdx.x;
    const int b = blk / NCHUNK;
    const int chunk = blk - b * NCHUNK;
    const int tid = threadIdx.x;
    const int n = chunk * 256 + tid;

    __shared__ unsigned long long list[LCAP];   // (p_bits<<32)|(cfg<<24)|n
    __shared__ int lcnt;
    __shared__ int ccnt[NFG];
    __shared__ int cbase[NFG];

    if (tid == 0) lcnt = 0;
    if (tid < NFG) ccnt[tid] = 0;
    __syncthreads();

    float m = 0.f, s = 1.f, thrv = 1e30f;
    const float* sc = scores;           // set properly below when n valid

    if (n < NBOX) {
        // ---- decode (bit-exact, validated rounds 1-6)
        const float* bb = bboxes + (size_t)b * 4 * NBOX + n;
        float bx = bb[0];
        float by = bb[NBOX];
        float bw = bb[2 * (size_t)NBOX];
        float bh = bb[3 * (size_t)NBOX];
        float4 d = reinterpret_cast<const float4*>(dboxes)[n];  // cx, cy, w, h
        float xx = __fadd_rn(__fmul_rn(__fmul_rn(0.1f, bx), d.z), d.x);
        float yy = __fadd_rn(__fmul_rn(__fmul_rn(0.1f, by), d.w), d.y);
        float wx = __fmul_rn(expf(__fmul_rn(0.2f, bw)), d.z);
        float wy = __fmul_rn(expf(__fmul_rn(0.2f, bh)), d.w);
        float4 o;
        o.x = __fsub_rn(xx, __fmul_rn(0.5f, wx));
        o.y = __fsub_rn(yy, __fmul_rn(0.5f, wy));
        o.z = __fadd_rn(xx, __fmul_rn(0.5f, wx));
        o.w = __fadd_rn(yy, __fmul_rn(0.5f, wy));
        ltrb[(size_t)b * NBOX + n] = o;

        // ---- softmax stats (vals[] dead after this scope)
        sc = scores + (size_t)b * NCLS * NBOX + n;
        {
            float vals[NCLS];
#pragma unroll
            for (int c = 0; c < NCLS; ++c) vals[c] = sc[(size_t)c * NBOX];
            m = vals[0];
#pragma unroll
            for (int c = 1; c < NCLS; ++c) m = fmaxf(m, vals[c]);
            float ss = 0.0f;
#pragma unroll
            for (int c = 0; c < NCLS; ++c) ss = __fadd_rn(ss, expf(__fsub_rn(vals[c], m)));
            s = ss;
        }
        // p > 0.05  =>  v > m + log(0.05*s); margin 1e-3 >> logf error;
        // survivors re-tested below with the exact reference expression.
        thrv = __fsub_rn(__fadd_rn(m, logf(__fmul_rn(0.05f, s))), 1e-3f);
    }

    // ---- phase 3: re-read logits via laundered pointer (prevents CSE with
    // vals[]), test, emit survivors to LDS list.
    if (n < NBOX) {
        uintptr_t scu = (uintptr_t)sc;
        asm volatile("" : "+v"(scu));
        const float* scv = (const float*)scu;
        for (int c0 = 1; c0 < NCLS; c0 += 16) {
            float vt[16];
#pragma unroll
            for (int u = 0; u < 16; ++u) {
                int c = c0 + u;
                vt[u] = (c < NCLS) ? scv[(size_t)c * NBOX] : -1e30f;
            }
#pragma unroll
            for (int u = 0; u < 16; ++u) {
                int c = c0 + u;
                if (vt[u] > thrv) {
                    // exact test — identical expression to validated rounds
                    float p = __fdiv_rn(expf(__fsub_rn(vt[u], m)), s);
                    if (p > SCORE_THR) {
                        int e = atomicAdd(&lcnt, 1);
                        if (e < LCAP)
                            list[e] = ((unsigned long long)__float_as_uint(p) << 32) |
                                      ((unsigned long long)(unsigned)(c - 1) << 24) |
                                      (unsigned long long)(unsigned)n;
                    }
                }
            }
        }
    }
    __syncthreads();

    const int E = min(lcnt, LCAP);

    // ---- phase 4: per-class histogram (LDS atomics)
    for (int i = tid; i < E; i += 256) {
        int c = (int)((list[i] >> 24) & 0xFF);
        atomicAdd(&ccnt[c], 1);
    }
    __syncthreads();

    // ---- phase 5: one global atomic per (block, class) to reserve ranges
    if (tid < NFG && ccnt[tid] > 0)
        cbase[tid] = atomicAdd(&gcnt[b * NFG + tid], ccnt[tid]);
    __syncthreads();
    if (tid < NFG) ccnt[tid] = 0;   // reuse as cursor
    __syncthreads();

    // ---- phase 6: scatter entries to reserved slots
    for (int i = tid; i < E; i += 256) {
        unsigned long long e = list[i];
        int c = (int)((e >> 24) & 0xFF);
        unsigned nn = (unsigned)(e & 0xFFFFFF);
        int pos = cbase[c] + atomicAdd(&ccnt[c], 1);
        if (pos < GCAP) {
            unsigned pb = (unsigned)(e >> 32);
            gcand[(size_t)(b * NFG + c) * GCAP + pos] =
                ((unsigned long long)pb << 32) |
                (unsigned long long)(0xFFFFFFFFu - nn);
        }
    }
}

// ---------------------------------------------------------------- K2: per-(image,class) list sort + NMS (round-3 structure)
__global__ __launch_bounds__(256) void k2_nms(
    const unsigned long long* __restrict__ gcand,  // [NTASK*GCAP]
    const int* __restrict__ gcnt,                  // [NTASK]
    const float4* __restrict__ ltrb,               // [B*N]
    float* __restrict__ cls_scores,                // [NTASK*200]
    int* __restrict__ cls_idx)                     // [NTASK*200] global ltrb index
{
    const int t = blockIdx.x;       // task = b*80 + (c-1)
    const int b = t / NFG;
    const int tid = threadIdx.x;

    // cand is dead after Phase C; mrow aliases it (saves 6.4 KB LDS)
    __shared__ unsigned long long cand[SORTCAP];                     // 8 KB
    unsigned long long (*mrow)[4] = (unsigned long long(*)[4])cand;  // [200][4]
    __shared__ float4 sbox[TOPK];
    __shared__ float sarea[TOPK];
    __shared__ float sscore[TOPK];
    __shared__ int sidx[TOPK];
    __shared__ unsigned long long keepw[4];

    const int cl = min(gcnt[t], SORTCAP);
    unsigned sz = 2;
    while (sz < (unsigned)cl) sz <<= 1;

    // load candidates + pad to pow2 with 0 (sorts to end, descending)
    const unsigned long long* gc = gcand + (size_t)t * GCAP;
    for (unsigned i = tid; i < sz; i += 256) cand[i] = (i < (unsigned)cl) ? gc[i] : 0ULL;
    __syncthreads();

    // Phase B: bitonic sort descending (score desc, idx asc) — keys unique => deterministic
    for (unsigned k = 2; k <= sz; k <<= 1) {
        for (unsigned j = k >> 1; j > 0; j >>= 1) {
            for (unsigned i = tid; i < sz; i += 256) {
                unsigned ixj = i ^ j;
                if (ixj > i) {
                    unsigned long long a = cand[i], bb2 = cand[ixj];
                    bool desc = ((i & k) == 0);
                    if (desc ? (a < bb2) : (a > bb2)) { cand[i] = bb2; cand[ixj] = a; }
                }
            }
            __syncthreads();
        }
    }

    const int mk = min(cl, TOPK);

    // Phase C: gather boxes for top-mk (cand dead after this)
    if (tid < mk) {
        unsigned long long key = cand[tid];
        unsigned n = 0xFFFFFFFFu - (unsigned)(key & 0xFFFFFFFFull);
        float4 bx = ltrb[(size_t)b * NBOX + n];
        sbox[tid] = bx;
        sarea[tid] = __fmul_rn(__fsub_rn(bx.z, bx.x), __fsub_rn(bx.w, bx.y));
        sscore[tid] = __uint_as_float((unsigned)(key >> 32));
        sidx[tid] = b * NBOX + (int)n;
    }
    __syncthreads();

    // Phase D: suppression bitmask rows (IoU replicates reference's unclamped deltas)
    if (tid < mk) {
        float4 bi = sbox[tid];
        float ai = sarea[tid];
#pragma unroll
        for (int q = 0; q < 4; ++q) {
            unsigned long long w = 0ULL;
            int j0 = q * 64;
            int j1 = min(mk, j0 + 64);
            for (int j2 = max(tid + 1, j0); j2 < j1; ++j2) {
                float4 bj = sbox[j2];
                float ltx = fmaxf(bi.x, bj.x), lty = fmaxf(bi.y, bj.y);
                float rbx = fminf(bi.z, bj.z), rby = fminf(bi.w, bj.w);
                float dx = __fsub_rn(rbx, ltx), dy = __fsub_rn(rby, lty);
                float inter = __fmul_rn(dx, dy);
                float uni = __fsub_rn(__fadd_rn(ai, sarea[j2]), inter);
                float iou = __fdiv_rn(inter, uni);
                if (iou >= CRITERIA) w |= 1ULL << (j2 - j0);
            }
            mrow[tid][q] = w;
        }
    }
    __syncthreads();

    // Phase E: greedy sequential pass (thread 0, LDS prefetch one row ahead)
    if (tid == 0) {
        auto maskBits = [](int r) -> unsigned long long {
            if (r <= 0) return 0ULL;
            if (r >= 64) return ~0ULL;
            return (1ULL << r) - 1ULL;
        };
        unsigned long long kw0 = maskBits(mk);
        unsigned long long kw1 = maskBits(mk - 64);
        unsigned long long kw2 = maskBits(mk - 128);
        unsigned long long kw3 = maskBits(mk - 192);
        unsigned long long r0 = 0, r1 = 0, r2 = 0, r3 = 0;
        if (mk > 0) { r0 = mrow[0][0]; r1 = mrow[0][1]; r2 = mrow[0][2]; r3 = mrow[0][3]; }
#define GREEDY_WORD(KW, BASE)                                                     \
        for (int bit2 = 0; bit2 < 64; ++bit2) {                                   \
            int i = (BASE) + bit2;                                                \
            if (i >= mk) break;                                                   \
            int ip = (i + 1 < mk) ? (i + 1) : i;                                  \
            unsigned long long n0 = mrow[ip][0], n1 = mrow[ip][1],                \
                               n2 = mrow[ip][2], n3 = mrow[ip][3];                \
            if ((KW >> bit2) & 1ULL) {                                            \
                kw0 &= ~r0; kw1 &= ~r1; kw2 &= ~r2; kw3 &= ~r3;                   \
            }                                                                     \
            r0 = n0; r1 = n1; r2 = n2; r3 = n3;                                   \
        }
        GREEDY_WORD(kw0, 0)
        GREEDY_WORD(kw1, 64)
        GREEDY_WORD(kw2, 128)
        GREEDY_WORD(kw3, 192)
#undef GREEDY_WORD
        keepw[0] = kw0; keepw[1] = kw1; keepw[2] = kw2; keepw[3] = kw3;
    }
    __syncthreads();

    // Phase F: write per-class results
    if (tid < TOPK) {
        float s = NEG_INF;
        if (tid < mk && ((keepw[tid >> 6] >> (tid & 63)) & 1ULL)) s = sscore[tid];
        cls_scores[(size_t)t * TOPK + tid] = s;
        if (tid < mk) cls_idx[(size_t)t * TOPK + tid] = sidx[tid];
    }
}

// ---------------------------------------------------------------- K3: per-image global top-200
__device__ __forceinline__ int blockReduceSum(int x, int* red, int tid) {
    __syncthreads();
    red[tid] = x;
    __syncthreads();
    for (int off = 128; off > 0; off >>= 1) {
        if (tid < off) red[tid] += red[tid + off];
        __syncthreads();
    }
    return red[0];
}

__global__ __launch_bounds__(256) void k3_topk(
    const float* __restrict__ cls_scores,   // [B*80*200]
    const int* __restrict__ cls_idx,        // [B*80*200]
    const float4* __restrict__ ltrb,        // [B*N]
    float* __restrict__ out)
{
    const int b = blockIdx.x;
    const int tid = threadIdx.x;
    const int NFLAT = NFG * TOPK;           // 16000
    const int PER = 63;

    __shared__ unsigned long long sel[512];
    __shared__ int scnt;
    __shared__ int red[256];

    const float* S = cls_scores + (size_t)b * NFLAT;
    float v[PER];
#pragma unroll
    for (int i = 0; i < PER; ++i) {
        int j = i * 256 + tid;
        v[i] = (j < NFLAT) ? S[j] : NEG_INF;
    }

    int lc = 0;
#pragma unroll
    for (int i = 0; i < PER; ++i) lc += (v[i] > -1e29f) ? 1 : 0;
    int validCount = blockReduceSum(lc, red, tid);

    unsigned thrBits = 0;
    if (validCount > TOPK) {
        unsigned lo = 0, hi = 0x7F800000u;
        while (lo < hi) {
            unsigned mid = (lo + hi) >> 1;
            float mf = __uint_as_float(mid);
            int c2 = 0;
#pragma unroll
            for (int i = 0; i < PER; ++i) c2 += (v[i] > mf) ? 1 : 0;
            int tot = blockReduceSum(c2, red, tid);
            if (tot < TOPK) hi = mid; else lo = mid + 1;
        }
        thrBits = lo;
    }

    __syncthreads();
    if (tid == 0) scnt = 0;
    for (int i = tid; i < 512; i += 256) sel[i] = 0ULL;
    __syncthreads();

    const bool useGE = (validCount > TOPK);
    const float thrF = __uint_as_float(thrBits);
#pragma unroll
    for (int i = 0; i < PER; ++i) {
        int j = i * 256 + tid;
        bool take = useGE ? (v[i] >= thrF) : (v[i] > -1e29f);
        if (j < NFLAT && take) {
            int pos = atomicAdd(&scnt, 1);
            if (pos < 512) {
                sel[pos] = ((unsigned long long)__float_as_uint(v[i]) << 32) |
                           (unsigned long long)(0xFFFFFFFFu - (unsigned)j);
            }
        }
    }
    __syncthreads();
    int total = min(min(scnt, 512), TOPK);

    for (unsigned k = 2; k <= 512; k <<= 1) {
        for (unsigned j = k >> 1; j > 0; j >>= 1) {
            for (unsigned i = tid; i < 512; i += 256) {
                unsigned ixj = i ^ j;
                if (ixj > i) {
                    unsigned long long a = sel[i], bb2 = sel[ixj];
                    bool desc = ((i & k) == 0);
                    if (desc ? (a < bb2) : (a > bb2)) { sel[i] = bb2; sel[ixj] = a; }
                }
            }
            __syncthreads();
        }
    }

    if (tid < TOPK) {
        size_t ob = (size_t)b * TOPK + tid;
        float4 bx = make_float4(0.f, 0.f, 0.f, 0.f);
        float lab = 0.f, sc2 = 0.f;
        if (tid < total) {
            unsigned long long key = sel[tid];
            unsigned j = 0xFFFFFFFFu - (unsigned)(key & 0xFFFFFFFFull);
            sc2 = __uint_as_float((unsigned)(key >> 32));
            unsigned cls = j / TOPK;
            int gi = cls_idx[(size_t)b * NFLAT + j];
            bx = ltrb[gi];
            lab = (float)(cls + 1);
        }
        reinterpret_cast<float4*>(out)[ob] = bx;
        out[(size_t)BATCH * TOPK * 4 + ob] = lab;
        out[(size_t)BATCH * TOPK * 4 + (size_t)BATCH * TOPK + ob] = sc2;
    }
}

// ---------------------------------------------------------------- launch
extern "C" void kernel_launch(void* const* d_in, const int* in_sizes, int n_in,
                              void* d_out, int out_size, void* d_ws, size_t ws_size,
                              hipStream_t stream) {
    (void)in_sizes; (void)n_in; (void)out_size; (void)ws_size;
    const float* bboxes = (const float*)d_in[0];   // [32,4,15130]
    const float* scores = (const float*)d_in[1];   // [32,81,15130]
    const float* dboxes = (const float*)d_in[2];   // [1,15130,4]
    float* out = (float*)d_out;

    char* ws = (char*)d_ws;
    size_t off = 0;
    float4* ltrb = (float4*)(ws + off);      off += (size_t)BATCH * NBOX * 16;    //  7,746,560
    unsigned long long* gcand = (unsigned long long*)(ws + off);
                                             off += (size_t)NTASK * GCAP * 8;     // 20,971,520
    float* cls_scores = (float*)(ws + off);  off += (size_t)NTASK * TOPK * 4;     //  2,048,000
    int*   cls_idx    = (int*)(ws + off);    off += (size_t)NTASK * TOPK * 4;     //  2,048,000
    int*   gcnt       = (int*)(ws + off);    off += (size_t)NTASK * 4;            //     10,240

    hipMemsetAsync(gcnt, 0, NTASK * sizeof(int), stream);

    k1_fused<<<BATCH * NCHUNK, 256, 0, stream>>>(bboxes, scores, dboxes, ltrb, gcand, gcnt);
    k2_nms<<<NTASK, 256, 0, stream>>>(gcand, gcnt, ltrb, cls_scores, cls_idx);
    k3_topk<<<BATCH, 256, 0, stream>>>(cls_scores, cls_idx, ltrb, out);
}